// Round 1
// baseline (664.593 us; speedup 1.0000x reference)
//
#include <hip/hip_runtime.h>
#include <hip/hip_cooperative_groups.h>
#include <cstddef>

namespace cg = cooperative_groups;

// Problem constants (all powers of two).
#define B_    128
#define IN_   256
#define OUT_  256
#define HS_   512

// Cooperative fused kernel geometry:
//  256 blocks x 512 threads, 1 block/CU (launch_bounds caps VGPR<=256).
//  4 rounds x 32 samples; per XCD (blk&7): 4 samples; 8 blocks/sample;
//  64 rows/block; 8 waves/block -> 8 rows/wave; hebb row fragment staged
//  in registers (8 rows x 8 floats = 64 VGPR) between phase 1 and phase 3.
#define NBLK_  256
#define NTHR_  512
#define ROUNDS_ 4

__device__ __forceinline__ float clip1(float x) {
    return fminf(fmaxf(x, -1.f), 1.f);
}

__global__ __launch_bounds__(NTHR_, 2) void fused_plastic(
    const float* __restrict__ inputs,   // [B, IN]
    const float* __restrict__ hidden,   // [B, HS]
    const float* __restrict__ hebb,     // [B, HS, HS]
    const float* __restrict__ i2h_w,    // [HS, IN]
    const float* __restrict__ i2h_b,    // [HS]
    const float* __restrict__ w,        // [HS, HS]
    const float* __restrict__ alpha,    // [HS, HS]
    const float* __restrict__ h2o_w,    // [OUT, HS]
    const float* __restrict__ h2o_b,    // [OUT]
    const float* __restrict__ h2v_w,    // [HS]
    const float* __restrict__ h2v_b,    // [1]
    const float* __restrict__ h2da_w,   // [HS]
    const float* __restrict__ h2da_b,   // [1]
    float* __restrict__ activout,       // [B, OUT]
    float* __restrict__ valueout,       // [B]
    float* __restrict__ hactiv,         // [B, HS]
    float* __restrict__ hebb_new,       // [B, HS, HS]
    float* __restrict__ ws_pd,          // [B*8] per-(sample,block) da partials
    float* __restrict__ ws_pv)          // [B*8] per-(sample,block) value partials
{
    cg::grid_group grid = cg::this_grid();

    const int blk  = blockIdx.x;
    const int xcd  = blk & 7;           // heuristic XCD id (perf-only)
    const int slot = blk >> 3;          // 0..31
    const int sub  = slot >> 3;         // 0..3  sample-within-xcd
    const int bs   = slot & 7;          // 0..7  block-within-sample
    const int tid  = threadIdx.x;
    const int wave = tid >> 6;          // 0..7
    const int lane = tid & 63;

    __shared__ float s_pd[8];
    __shared__ float s_pv[8];
    __shared__ float s_h[HS_];
    __shared__ float s_part[128 * 4];

    for (int r = 0; r < ROUNDS_; ++r) {
        const int b = r * 32 + xcd * 4 + sub;

        // Lane-fixed per-sample operands.
        const float4* hid4 = (const float4*)(hidden + (size_t)b * HS_);
        const float4 h0  = hid4[lane];
        const float4 h1  = hid4[lane + 64];
        const float4 in4 = ((const float4*)(inputs + (size_t)b * IN_))[lane];

        const int i_base = bs * 64 + wave * 8;

        float hb_s[8][8];   // staged hebb fragments (registers)
        float h_row[8];     // hactiv for this wave's 8 rows (all lanes)
        float pd = 0.f, pv = 0.f;

        // ---- phase 1: hactiv + da/value partials; hebb staged to regs ----
        #pragma unroll
        for (int q = 0; q < 8; ++q) {
            const int i = i_base + q;
            const float4* hbp = (const float4*)(hebb + ((size_t)b * HS_ + i) * HS_);
            const float4 hb0 = hbp[lane];
            const float4 hb1 = hbp[lane + 64];
            const float4* wr = (const float4*)(w     + (size_t)i * HS_);
            const float4* ar = (const float4*)(alpha + (size_t)i * HS_);
            const float4 wv0 = wr[lane], wv1 = wr[lane + 64];
            const float4 av0 = ar[lane], av1 = ar[lane + 64];
            const float4 iw  = ((const float4*)(i2h_w + (size_t)i * IN_))[lane];

            float acc;
            acc  = (wv0.x + av0.x * hb0.x) * h0.x;
            acc += (wv0.y + av0.y * hb0.y) * h0.y;
            acc += (wv0.z + av0.z * hb0.z) * h0.z;
            acc += (wv0.w + av0.w * hb0.w) * h0.w;
            acc += (wv1.x + av1.x * hb1.x) * h1.x;
            acc += (wv1.y + av1.y * hb1.y) * h1.y;
            acc += (wv1.z + av1.z * hb1.z) * h1.z;
            acc += (wv1.w + av1.w * hb1.w) * h1.w;
            acc += iw.x * in4.x + iw.y * in4.y + iw.z * in4.z + iw.w * in4.w;

            // 64-lane butterfly all-reduce: every lane gets the row sum.
            #pragma unroll
            for (int off = 1; off < 64; off <<= 1)
                acc += __shfl_xor(acc, off, 64);

            const float h = tanhf(acc + i2h_b[i]);
            h_row[q] = h;

            hb_s[q][0] = hb0.x; hb_s[q][1] = hb0.y; hb_s[q][2] = hb0.z; hb_s[q][3] = hb0.w;
            hb_s[q][4] = hb1.x; hb_s[q][5] = hb1.y; hb_s[q][6] = hb1.z; hb_s[q][7] = hb1.w;

            if (lane == 0) {
                hactiv[(size_t)b * HS_ + i] = h;
                pd += h * h2da_w[i];
                pv += h * h2v_w[i];
            }
        }

        // block-level partial reduction -> workspace (plain stores, no atomics)
        if (lane == 0) { s_pd[wave] = pd; s_pv[wave] = pv; }
        __syncthreads();
        if (tid == 0) {
            float sd = 0.f, sv = 0.f;
            #pragma unroll
            for (int k = 0; k < 8; ++k) { sd += s_pd[k]; sv += s_pv[k]; }
            ws_pd[b * 8 + bs] = sd;
            ws_pv[b * 8 + bs] = sv;
        }
        __threadfence();
        grid.sync();

        // ---- phase 3: finalize da, update hebb from staged registers ----
        float sd = 0.f, sv = 0.f;
        #pragma unroll
        for (int k = 0; k < 8; ++k) {
            sd += ws_pd[b * 8 + k];
            sv += ws_pv[b * 8 + k];
        }
        const float da_b = tanhf(sd + h2da_b[0]);
        if (bs == 0 && tid == 0)
            valueout[b] = sv + h2v_b[0];

        #pragma unroll
        for (int q = 0; q < 8; ++q) {
            const int i = i_base + q;
            const float sc = da_b * h_row[q];
            float4 o0, o1;
            o0.x = clip1(fmaf(sc, h0.x, hb_s[q][0]));
            o0.y = clip1(fmaf(sc, h0.y, hb_s[q][1]));
            o0.z = clip1(fmaf(sc, h0.z, hb_s[q][2]));
            o0.w = clip1(fmaf(sc, h0.w, hb_s[q][3]));
            o1.x = clip1(fmaf(sc, h1.x, hb_s[q][4]));
            o1.y = clip1(fmaf(sc, h1.y, hb_s[q][5]));
            o1.z = clip1(fmaf(sc, h1.z, hb_s[q][6]));
            o1.w = clip1(fmaf(sc, h1.w, hb_s[q][7]));
            float4* op = (float4*)(hebb_new + ((size_t)b * HS_ + i) * HS_);
            op[lane]      = o0;
            op[lane + 64] = o1;
        }
    }

    // ---- heads tail: activout (all hactiv visible since last grid.sync) ----
    // block -> (sample ba, half ha); xcd-affine mapping (perf-only).
    const int k16 = slot >> 1;                       // 0..15
    const int ha  = slot & 1;
    const int ba  = (k16 >> 2) * 32 + xcd * 4 + (k16 & 3);

    __syncthreads();
    if (tid < 128)
        ((float4*)s_h)[tid] = ((const float4*)(hactiv + (size_t)ba * HS_))[tid];
    __syncthreads();

    {
        const int oo = tid & 127;
        const int qq = tid >> 7;                     // 0..3 quarter of the dot
        const int o  = ha * 128 + oo;
        const float4* wp = (const float4*)(h2o_w + (size_t)o * HS_);
        const float4* hp = (const float4*)s_h;
        float acc = 0.f;
        #pragma unroll 8
        for (int c = 0; c < 32; ++c) {
            const float4 wv = wp[qq * 32 + c];
            const float4 hv = hp[qq * 32 + c];
            acc += wv.x * hv.x + wv.y * hv.y + wv.z * hv.z + wv.w * hv.w;
        }
        s_part[qq * 128 + oo] = acc;
    }
    __syncthreads();
    if (tid < 128) {
        const int o = ha * 128 + tid;
        activout[(size_t)ba * OUT_ + o] =
            s_part[tid] + s_part[128 + tid] + s_part[256 + tid] + s_part[384 + tid]
            + h2o_b[o];
    }
}

// ---------------------------------------------------------------------------
// Fallback path (previous verified 3-kernel version) — used only if the
// workspace is too small for the cooperative path's 8 KB of partials.
// ---------------------------------------------------------------------------
__global__ __launch_bounds__(256) void k1_hactiv(
    const float* __restrict__ inputs, const float* __restrict__ hidden,
    const float* __restrict__ hebb, const float* __restrict__ i2h_w,
    const float* __restrict__ i2h_b, const float* __restrict__ w,
    const float* __restrict__ alpha, float* __restrict__ hactiv)
{
    const int b     = blockIdx.x & (B_ - 1);
    const int chunk = blockIdx.x >> 7;
    const int tid   = threadIdx.x;
    const int wave  = tid >> 6;
    const int lane  = tid & 63;

    const float4* hid4 = (const float4*)(hidden + (size_t)b * HS_);
    const float4  h0   = hid4[lane];
    const float4  h1   = hid4[lane + 64];
    const float4  in4  = ((const float4*)(inputs + (size_t)b * IN_))[lane];

    const int i0 = chunk * 64 + wave * 16;

    for (int r = 0; r < 16; ++r) {
        const int i = i0 + r;
        const float4* hb = (const float4*)(hebb + ((size_t)b * HS_ + i) * HS_);
        const float4* wr = (const float4*)(w     + (size_t)i * HS_);
        const float4* ar = (const float4*)(alpha + (size_t)i * HS_);

        const float4 hb0 = hb[lane];
        const float4 hb1 = hb[lane + 64];
        const float4 wv0 = wr[lane];
        const float4 wv1 = wr[lane + 64];
        const float4 av0 = ar[lane];
        const float4 av1 = ar[lane + 64];
        const float4 iw  = ((const float4*)(i2h_w + (size_t)i * IN_))[lane];

        float acc;
        acc  = (wv0.x + av0.x * hb0.x) * h0.x;
        acc += (wv0.y + av0.y * hb0.y) * h0.y;
        acc += (wv0.z + av0.z * hb0.z) * h0.z;
        acc += (wv0.w + av0.w * hb0.w) * h0.w;
        acc += (wv1.x + av1.x * hb1.x) * h1.x;
        acc += (wv1.y + av1.y * hb1.y) * h1.y;
        acc += (wv1.z + av1.z * hb1.z) * h1.z;
        acc += (wv1.w + av1.w * hb1.w) * h1.w;
        acc += iw.x * in4.x + iw.y * in4.y + iw.z * in4.z + iw.w * in4.w;

        #pragma unroll
        for (int off = 32; off > 0; off >>= 1)
            acc += __shfl_down(acc, off, 64);

        if (lane == 0)
            hactiv[(size_t)b * HS_ + i] = tanhf(acc + i2h_b[i]);
    }
}

__global__ __launch_bounds__(256) void k2_heads(
    const float* __restrict__ hactiv, const float* __restrict__ h2o_w,
    const float* __restrict__ h2o_b, const float* __restrict__ h2v_w,
    const float* __restrict__ h2v_b, const float* __restrict__ h2da_w,
    const float* __restrict__ h2da_b, float* __restrict__ activout,
    float* __restrict__ valueout, float* __restrict__ da)
{
    const int b   = blockIdx.x;
    const int tid = threadIdx.x;

    __shared__ float s_h[HS_];
    __shared__ float red_v[256];
    __shared__ float red_d[256];

    for (int t = tid; t < HS_; t += 256)
        s_h[t] = hactiv[(size_t)b * HS_ + t];
    __syncthreads();

    const float4* wr  = (const float4*)(h2o_w + (size_t)tid * HS_);
    const float4* sh4 = (const float4*)s_h;
    float acc = 0.f;
    #pragma unroll 4
    for (int q = 0; q < HS_ / 4; ++q) {
        const float4 wv = wr[q];
        const float4 hv = sh4[q];
        acc += wv.x * hv.x + wv.y * hv.y + wv.z * hv.z + wv.w * hv.w;
    }
    activout[(size_t)b * OUT_ + tid] = acc + h2o_b[tid];

    float pv = 0.f, pd = 0.f;
    for (int t = tid; t < HS_; t += 256) {
        const float hv = s_h[t];
        pv += hv * h2v_w[t];
        pd += hv * h2da_w[t];
    }
    red_v[tid] = pv;
    red_d[tid] = pd;
    __syncthreads();
    for (int s = 128; s > 0; s >>= 1) {
        if (tid < s) {
            red_v[tid] += red_v[tid + s];
            red_d[tid] += red_d[tid + s];
        }
        __syncthreads();
    }
    if (tid == 0) {
        valueout[b] = red_v[0] + h2v_b[0];
        da[b]       = tanhf(red_d[0] + h2da_b[0]);
    }
}

__global__ __launch_bounds__(256) void k3_hebb(
    const float* __restrict__ hebb, const float* __restrict__ hidden,
    const float* __restrict__ hactiv, const float* __restrict__ da,
    float* __restrict__ hebb_new)
{
    const int tid = threadIdx.x;
    const size_t base = (size_t)blockIdx.x * 1024;

    #pragma unroll
    for (int k = 0; k < 4; ++k) {
        const size_t idx = base + (size_t)k * 256 + tid;
        const int j4  = (int)(idx & 127);
        const int row = (int)(idx >> 7);
        const int i   = row & (HS_ - 1);
        const int b   = row >> 9;

        const float scale = da[b] * hactiv[(size_t)b * HS_ + i];
        const float4 hv = ((const float4*)hebb)[idx];
        const float4 hd = ((const float4*)hidden)[(size_t)b * (HS_ / 4) + j4];

        float4 r;
        r.x = fminf(fmaxf(fmaf(scale, hd.x, hv.x), -1.f), 1.f);
        r.y = fminf(fmaxf(fmaf(scale, hd.y, hv.y), -1.f), 1.f);
        r.z = fminf(fmaxf(fmaf(scale, hd.z, hv.z), -1.f), 1.f);
        r.w = fminf(fmaxf(fmaf(scale, hd.w, hv.w), -1.f), 1.f);
        ((float4*)hebb_new)[idx] = r;
    }
}

// ---------------------------------------------------------------------------
extern "C" void kernel_launch(void* const* d_in, const int* in_sizes, int n_in,
                              void* d_out, int out_size, void* d_ws, size_t ws_size,
                              hipStream_t stream)
{
    const float* inputs = (const float*)d_in[0];
    const float* hidden = (const float*)d_in[1];
    const float* hebb   = (const float*)d_in[2];
    const float* i2h_w  = (const float*)d_in[3];
    const float* i2h_b  = (const float*)d_in[4];
    const float* w      = (const float*)d_in[5];
    const float* alpha  = (const float*)d_in[6];
    const float* h2o_w  = (const float*)d_in[7];
    const float* h2o_b  = (const float*)d_in[8];
    const float* h2v_w  = (const float*)d_in[9];
    const float* h2v_b  = (const float*)d_in[10];
    const float* h2da_w = (const float*)d_in[11];
    const float* h2da_b = (const float*)d_in[12];

    float* out = (float*)d_out;
    // Output layout (flat, return order): activout | valueout | hactiv | hebb_new
    float* activout = out;                              // 128*256   = 32768
    float* valueout = out + 32768;                      // 128
    float* hactiv   = out + 32768 + 128;                // 128*512   = 65536
    float* hebb_new = out + 32768 + 128 + 65536;        // 128*512*512

    if (ws_size >= (size_t)(2 * B_ * 8 * sizeof(float))) {
        float* ws_pd = (float*)d_ws;                    // [128*8]
        float* ws_pv = ws_pd + B_ * 8;                  // [128*8]

        void* args[] = {
            (void*)&inputs, (void*)&hidden, (void*)&hebb, (void*)&i2h_w,
            (void*)&i2h_b,  (void*)&w,      (void*)&alpha, (void*)&h2o_w,
            (void*)&h2o_b,  (void*)&h2v_w,  (void*)&h2v_b, (void*)&h2da_w,
            (void*)&h2da_b, (void*)&activout, (void*)&valueout,
            (void*)&hactiv, (void*)&hebb_new, (void*)&ws_pd, (void*)&ws_pv
        };
        hipLaunchCooperativeKernel((const void*)fused_plastic,
                                   dim3(NBLK_), dim3(NTHR_), args, 0, stream);
    } else {
        float* da = (float*)d_ws;                       // [128] scratch
        k1_hactiv<<<dim3(1024), dim3(256), 0, stream>>>(
            inputs, hidden, hebb, i2h_w, i2h_b, w, alpha, hactiv);
        k2_heads<<<dim3(B_), dim3(256), 0, stream>>>(
            hactiv, h2o_w, h2o_b, h2v_w, h2v_b, h2da_w, h2da_b,
            activout, valueout, da);
        k3_hebb<<<dim3(8192), dim3(256), 0, stream>>>(
            hebb, hidden, hactiv, da, hebb_new);
    }
}